// Round 3
// baseline (1557.336 us; speedup 1.0000x reference)
//
#include <hip/hip_runtime.h>
#include <hip/hip_bf16.h>
#include <cstdint>
#include <cstddef>

// ---------------- JAX threefry2x32 (partitionable scheme) — FROZEN (verified R1)
struct TF2 { uint32_t a, b; };

__host__ __device__ constexpr uint32_t rotl32(uint32_t v, int r) {
  return (v << r) | (v >> (32 - r));
}

__host__ __device__ constexpr TF2 threefry2x32(uint32_t k0, uint32_t k1,
                                               uint32_t x0, uint32_t x1) {
  uint32_t ks0 = k0, ks1 = k1, ks2 = k0 ^ k1 ^ 0x1BD11BDAu;
  const int rotA[4] = {13, 15, 26, 6};
  const int rotB[4] = {17, 29, 16, 24};
  x0 += ks0; x1 += ks1;
  for (int i = 0; i < 5; ++i) {
    const int* rot = (i % 2 == 0) ? rotA : rotB;
    for (int j = 0; j < 4; ++j) {
      x0 += x1; x1 = rotl32(x1, rot[j]); x1 ^= x0;
    }
    uint32_t ks[3] = {ks0, ks1, ks2};
    x0 += ks[(i + 1) % 3];
    x1 += ks[(i + 2) % 3] + (uint32_t)(i + 1);
  }
  return TF2{x0, x1};
}

__device__ __forceinline__ float jax_mask(uint32_t child, uint32_t idx) {
  TF2 ck = threefry2x32(0u, 42u, 0u, child);   // constant-folds
  TF2 r  = threefry2x32(ck.a, ck.b, 0u, idx);
  uint32_t bits = r.a ^ r.b;
  float u = __uint_as_float((bits >> 9) | 0x3f800000u) - 1.0f;
  return (u < 0.7f) ? (1.0f / 0.7f) : 0.0f;
}

__device__ __forceinline__ unsigned short f2bf(float f) {
  uint32_t u = __float_as_uint(f);
  uint32_t r = (u + 0x7fffu + ((u >> 16) & 1u)) >> 16;   // RNE
  return (unsigned short)r;
}

__device__ __forceinline__ float bf2f(unsigned short b) {
  return __uint_as_float((uint32_t)b << 16);
}

typedef __attribute__((ext_vector_type(8))) short short8;
typedef __attribute__((ext_vector_type(4))) float f32x4;

// async global->LDS, 16B per lane. LDS dest = wave-uniform base + lane*16.
__device__ __forceinline__ void async_copy16(const unsigned short* g, unsigned short* l) {
  __builtin_amdgcn_global_load_lds(
      (const __attribute__((address_space(1))) unsigned int*)g,
      (__attribute__((address_space(3))) unsigned int*)l, 16, 0, 0);
}

// ---------------- build x (bf16) = [image_emb ; emb_table[targets]*word_mask]
__global__ __launch_bounds__(256) void build_x_kernel(
    const float* __restrict__ img, const int* __restrict__ tgt,
    const float* __restrict__ emb, unsigned short* __restrict__ x) {
  const int idx = blockIdx.x * 256 + threadIdx.x;   // b*32768 + t*512 + e
  const int e = idx & 511;
  const int t = (idx >> 9) & 63;
  const int b = idx >> 15;
  float v;
  if (t == 0) {
    v = img[b * 512 + e];
  } else {
    const int w = tgt[b * 64 + (t - 1)];
    const float wm = jax_mask(0u, (uint32_t)(b * 512 + e));
    v = emb[(size_t)w * 512 + e] * wm;
  }
  x[idx] = f2bf(v);
}

// ---------------- transpose W_rec (512x2048) -> WT (2048x512) fp32 -------
__global__ __launch_bounds__(256) void transpose_wrec(
    const float* __restrict__ in, float* __restrict__ out) {
  __shared__ float tile[32][33];
  const int j0 = blockIdx.x * 32;
  const int u0 = blockIdx.y * 32;
  const int tx = threadIdx.x & 31;
  const int ty = threadIdx.x >> 5;
  for (int r = ty; r < 32; r += 8)
    tile[r][tx] = in[(size_t)(u0 + r) * 2048 + (j0 + tx)];
  __syncthreads();
  for (int r = ty; r < 32; r += 8)
    out[(size_t)(j0 + r) * 512 + (u0 + tx)] = tile[tx][r];
}

// ------- transpose+convert fp32 [R][C] -> bf16 [C][R]  (R=512 here) ------
__global__ __launch_bounds__(256) void transpose_cvt(
    const float* __restrict__ in, unsigned short* __restrict__ out,
    int R, int C) {
  __shared__ float tile[32][33];
  const int c0 = blockIdx.x * 32;
  const int r0 = blockIdx.y * 32;
  const int tx = threadIdx.x & 31;
  const int ty = threadIdx.x >> 5;
  for (int r = ty; r < 32; r += 8)
    tile[r][tx] = in[(size_t)(r0 + r) * C + (c0 + tx)];
  __syncthreads();
  for (int r = ty; r < 32; r += 8)
    out[(size_t)(c0 + r) * R + (r0 + tx)] = f2bf(tile[tx][r]);
}

// ---------------- bf16 MFMA GEMM: C[M][N] = A[M][512] * BT[N][512]^T + bias
// 128x128 tile, BK=32, 16x16x32 MFMA, fp32 accum. m97 structure.
__global__ __launch_bounds__(256) void gemm_bf16_mfma(
    const unsigned short* __restrict__ A, const unsigned short* __restrict__ BT,
    const float* __restrict__ bias, float* __restrict__ C, int M, int N) {
  __shared__ unsigned short As[128 * 32];   // [m][k] rows of 32 bf16 (64B)
  __shared__ unsigned short Bs[128 * 32];   // [n][k]
  const int tid = threadIdx.x;
  const int lane = tid & 63;
  const int wave = tid >> 6;              // 0..3
  const int wm = (wave >> 1) * 64;
  const int wn = (wave & 1) * 64;
  const int m0 = blockIdx.y * 128;
  const int n0 = blockIdx.x * 128;

  f32x4 zero4 = {0.f, 0.f, 0.f, 0.f};
  f32x4 acc[4][4];
#pragma unroll
  for (int i = 0; i < 4; ++i)
#pragma unroll
    for (int j = 0; j < 4; ++j) acc[i][j] = zero4;

  // staging: thread covers row tid/4 (and +64), 16B chunk tid%4
  const unsigned short* ga = A + (size_t)(m0 + (tid >> 2)) * 512 + (tid & 3) * 8;
  const unsigned short* gb = BT + (size_t)(n0 + (tid >> 2)) * 512 + (tid & 3) * 8;
  unsigned short* lwA = As + wave * 512;   // + lane*16B by HW
  unsigned short* lwB = Bs + wave * 512;

  const int fr = lane & 15;
  const int kc = (lane >> 4) * 8;

  for (int k0 = 0; k0 < 512; k0 += 32) {
    __syncthreads();   // previous frag reads done before overwrite
    async_copy16(ga + k0, lwA);
    async_copy16(ga + k0 + 64 * 512, lwA + 2048);
    async_copy16(gb + k0, lwB);
    async_copy16(gb + k0 + 64 * 512, lwB + 2048);
    __syncthreads();   // drain vmcnt: LDS tiles ready

    short8 af[4], bf[4];
#pragma unroll
    for (int i = 0; i < 4; ++i)
      af[i] = *(const short8*)(As + (wm + i * 16 + fr) * 32 + kc);
#pragma unroll
    for (int i = 0; i < 4; ++i)
      bf[i] = *(const short8*)(Bs + (wn + i * 16 + fr) * 32 + kc);
#pragma unroll
    for (int mi = 0; mi < 4; ++mi)
#pragma unroll
      for (int ni = 0; ni < 4; ++ni)
        acc[mi][ni] = __builtin_amdgcn_mfma_f32_16x16x32_bf16(
            af[mi], bf[ni], acc[mi][ni], 0, 0, 0);
  }

  // epilogue: C row = quad*4+reg, col = lane&15 (m89-verified layout)
#pragma unroll
  for (int mi = 0; mi < 4; ++mi) {
    const int mrow = m0 + wm + mi * 16 + (lane >> 4) * 4;
#pragma unroll
    for (int ni = 0; ni < 4; ++ni) {
      const int ncol = n0 + wn + ni * 16 + (lane & 15);
      const float bs = bias[ncol];
#pragma unroll
      for (int r2 = 0; r2 < 4; ++r2)
        C[(size_t)(mrow + r2) * N + ncol] = acc[mi][ni][r2] + bs;
    }
  }
}

// ---------------- fused LSTM scan: ONE persistent kernel, 64 steps -------
// 32 blocks x 512 threads (8 waves; 1 block/CU). Waves 0-3: gates, K-half 0;
// waves 4-7: gates, K-half 1. W_rec frags (bf16 hi+lo) live in registers.
// h crosses blocks via PACKED uint32 planes accessed ONLY with relaxed
// AGENT-scope atomics (sc1 -> coherence point; no L1/L2 staleness), so the
// grid barrier needs NO __threadfence (no buffer_wbl2 / buffer_inv).
// hm word layout per parity: [plane hi=0/lo=1][gate][b][k/2], word =
// bf16(k) | bf16(k+1)<<16.  Words/parity = 2*4*32*256 = 65536 (256 KB).
#define HMW 65536
#define NBLK 32

__device__ __forceinline__ void grid_barrier(unsigned int* bar, unsigned int target) {
  asm volatile("s_waitcnt vmcnt(0)" ::: "memory");   // hm stores acked @ coherence pt
  __syncthreads();
  if (threadIdx.x == 0) {
    __hip_atomic_fetch_add(bar, 1u, __ATOMIC_RELAXED, __HIP_MEMORY_SCOPE_AGENT);
    while (__hip_atomic_load(bar, __ATOMIC_RELAXED, __HIP_MEMORY_SCOPE_AGENT) < target)
      __builtin_amdgcn_s_sleep(1);
  }
  __syncthreads();
}

__device__ __forceinline__ unsigned long long hm_ld(const unsigned long long* p) {
  return __hip_atomic_load(p, __ATOMIC_RELAXED, __HIP_MEMORY_SCOPE_AGENT);
}

__global__ __launch_bounds__(512, 1) void lstm_coop(
    const float* __restrict__ zin, const float* __restrict__ WT,
    uint32_t* __restrict__ hm, unsigned short* __restrict__ rnn,
    unsigned int* __restrict__ bar) {
  __shared__ float zsh[2][4][32][17];
  const int tid = threadIdx.x;
  const int lane = tid & 63;
  const int wv = tid >> 6;                // 0..7
  const int g = wv & 3;                   // gate
  const int half = wv >> 2;               // K half (0: k<256, 1: k>=256)
  const int u0 = blockIdx.x * 16;
  const int fr = lane & 15;
  const int kq = (lane >> 4) * 8;

  // ---- one-time: W fragments (bf16 hi/lo) into registers ----------------
  // B-frag for 16x16x32: lane holds W[col = u0+fr][k = half*256 + j*32 + kq ..+8]
  short8 whi[8], wlo[8];
  {
    const float* wrow = WT + (size_t)(g * 512 + u0 + fr) * 512 + half * 256 + kq;
#pragma unroll
    for (int j = 0; j < 8; ++j) {
      const float4 w0 = *(const float4*)(wrow + j * 32);
      const float4 w1 = *(const float4*)(wrow + j * 32 + 4);
      const float wvv[8] = {w0.x, w0.y, w0.z, w0.w, w1.x, w1.y, w1.z, w1.w};
      short8 h8, l8;
#pragma unroll
      for (int e = 0; e < 8; ++e) {
        const unsigned short hb = f2bf(wvv[e]);
        h8[e] = (short)hb;
        l8[e] = (short)f2bf(wvv[e] - bf2f(hb));
      }
      whi[j] = h8; wlo[j] = l8;
    }
  }

  // ---- per-thread activation constants (512 threads = 512 cells) --------
  const int ab = tid >> 4;            // batch 0..31
  const int uc = tid & 15;
  const int au = u0 + uc;             // global u
  float rmask[4];
#pragma unroll
  for (int gg = 0; gg < 4; ++gg)
    rmask[gg] = jax_mask(1u, (uint32_t)((gg * 32 + ab) * 512 + au));
  float cs = 0.f;

  // per-lane hm qword bases (per parity; lo plane at +16384 qwords)
  const size_t qrow0 = ((size_t)((g * 32 + fr) * 256)) >> 1;      // row fr
  const size_t qk0   = qrow0 + (size_t)(half * 64) + (kq >> 2);   // + j*8

  for (int t = 0; t < 64; ++t) {
    const int rp = t & 1;             // read parity (t=0 skips reads)
    // prefetch zin (independent of barrier/hm)
    const size_t zo = (size_t)(ab * 64 + t) * 2048 + au;
    const float z0 = zin[zo], z1 = zin[zo + 512];
    const float z2 = zin[zo + 1024], z3 = zin[zo + 1536];

    f32x4 ahh0 = {0,0,0,0}, ahl0 = {0,0,0,0}, alh0 = {0,0,0,0};
    f32x4 ahh1 = {0,0,0,0}, ahl1 = {0,0,0,0}, alh1 = {0,0,0,0};

    if (t) {
      const unsigned long long* q =
          (const unsigned long long*)(hm + (size_t)rp * HMW);
#pragma unroll
      for (int j = 0; j < 8; ++j) {
        const size_t qo = qk0 + (size_t)(j * 8);
        union { unsigned long long w[2]; short8 s; } h0, h1, l0, l1;
        h0.w[0] = hm_ld(q + qo);             h0.w[1] = hm_ld(q + qo + 1);
        h1.w[0] = hm_ld(q + qo + 2048);      h1.w[1] = hm_ld(q + qo + 2049);
        l0.w[0] = hm_ld(q + qo + 16384);     l0.w[1] = hm_ld(q + qo + 16385);
        l1.w[0] = hm_ld(q + qo + 18432);     l1.w[1] = hm_ld(q + qo + 18433);
        ahh0 = __builtin_amdgcn_mfma_f32_16x16x32_bf16(h0.s, whi[j], ahh0, 0, 0, 0);
        ahh1 = __builtin_amdgcn_mfma_f32_16x16x32_bf16(h1.s, whi[j], ahh1, 0, 0, 0);
        ahl0 = __builtin_amdgcn_mfma_f32_16x16x32_bf16(h0.s, wlo[j], ahl0, 0, 0, 0);
        ahl1 = __builtin_amdgcn_mfma_f32_16x16x32_bf16(h1.s, wlo[j], ahl1, 0, 0, 0);
        alh0 = __builtin_amdgcn_mfma_f32_16x16x32_bf16(l0.s, whi[j], alh0, 0, 0, 0);
        alh1 = __builtin_amdgcn_mfma_f32_16x16x32_bf16(l1.s, whi[j], alh1, 0, 0, 0);
      }
    }

    // scatter partial z_rec to LDS: row = (lane>>4)*4 + r (+16), col = fr
#pragma unroll
    for (int r = 0; r < 4; ++r) {
      zsh[half][g][(lane >> 4) * 4 + r][fr]      = ahh0[r] + ahl0[r] + alh0[r];
      zsh[half][g][16 + (lane >> 4) * 4 + r][fr] = ahh1[r] + ahl1[r] + alh1[r];
    }
    __syncthreads();

    // activation: 1 cell per thread (b = ab, u = au)
    const float zi = zsh[0][0][ab][uc] + zsh[1][0][ab][uc] + z0;
    const float zf = zsh[0][1][ab][uc] + zsh[1][1][ab][uc] + z1;
    const float zg = zsh[0][2][ab][uc] + zsh[1][2][ab][uc] + z2;
    const float zz = zsh[0][3][ab][uc] + zsh[1][3][ab][uc] + z3;
    const float i_ = 1.f / (1.f + expf(-zi));
    const float f_ = 1.f / (1.f + expf(-zf));
    const float g_ = tanhf(zg);
    const float o_ = 1.f / (1.f + expf(-zz));
    cs = f_ * cs + i_ * g_;
    const float hn = o_ * tanhf(cs);
    const float fm = jax_mask(2u, (uint32_t)((ab * 64 + t) * 512 + au));
    rnn[(size_t)(ab * 64 + t) * 512 + au] = f2bf(hn * fm);

    if (t < 63) {
      // write masked h (packed hi|lo planes) for next step, opposite parity
      uint32_t* hw = hm + (size_t)(rp ^ 1) * HMW;
      const int kp = au >> 1;
#pragma unroll
      for (int gg = 0; gg < 4; ++gg) {
        const float v = hn * rmask[gg];
        const unsigned short hb16 = f2bf(v);
        const unsigned short lb16 = f2bf(v - bf2f(hb16));
        const unsigned mine = (unsigned)hb16 | ((unsigned)lb16 << 16);
        const unsigned oth = (unsigned)__shfl_xor((int)mine, 1, 64);
        if (!(uc & 1)) {
          const unsigned hiw = (mine & 0xFFFFu) | (oth << 16);
          const unsigned low = (mine >> 16) | (oth & 0xFFFF0000u);
          const size_t wi = (size_t)(gg * 32 + ab) * 256 + kp;
          __hip_atomic_store(hw + wi, hiw,
                             __ATOMIC_RELAXED, __HIP_MEMORY_SCOPE_AGENT);
          __hip_atomic_store(hw + 32768 + wi, low,
                             __ATOMIC_RELAXED, __HIP_MEMORY_SCOPE_AGENT);
        }
      }
      // grid-wide barrier: all hm writes @ coherence pt before anyone reads
      grid_barrier(bar, (unsigned int)(NBLK * (t + 1)));
    }
  }
}

// ---------------- launch -------------------------------------------------
extern "C" void kernel_launch(void* const* d_in, const int* in_sizes, int n_in,
                              void* d_out, int out_size, void* d_ws, size_t ws_size,
                              hipStream_t stream) {
  (void)in_sizes; (void)n_in; (void)out_size; (void)ws_size;
  const float* img   = (const float*)d_in[1];
  const int*   tgt   = (const int*)d_in[2];
  const float* emb   = (const float*)d_in[3];
  const float* W_in  = (const float*)d_in[4];
  const float* W_rec = (const float*)d_in[5];
  const float* b_l   = (const float*)d_in[6];
  const float* W_out = (const float*)d_in[7];
  const float* b_o   = (const float*)d_in[8];
  float* out = (float*)d_out;
  float* ws  = (float*)d_ws;

  float* zin = ws;                       // 4,194,304 f (16 MB)
  float* WT  = ws + 4194304;             // 1,048,576 f (4 MB)
  uint32_t* hm = (uint32_t*)(ws + 5242880);  // 2*HMW words (512 KB)
  unsigned int* bar  = (unsigned int*)(ws + 5440000);    // grid barrier counter
  unsigned short* us = (unsigned short*)(ws + 5455872);
  unsigned short* x_bf  = us;            // 1,048,576 us (2 MB)
  unsigned short* WinT  = us + 1048576;  // 1,048,576 us
  unsigned short* rnn   = us + 2097152;  // 1,048,576 us
  unsigned short* WoutT = us + 3145728;  // 16,384,000 us (32.8 MB)

  hipMemsetAsync(bar, 0, 64, stream);    // reset barrier epoch counter

  build_x_kernel<<<4096, 256, 0, stream>>>(img, tgt, emb, x_bf);
  transpose_wrec<<<dim3(64, 16), 256, 0, stream>>>(W_rec, WT);
  transpose_cvt<<<dim3(64, 16), 256, 0, stream>>>(W_in, WinT, 512, 2048);
  transpose_cvt<<<dim3(1000, 16), 256, 0, stream>>>(W_out, WoutT, 512, 32000);

  // z_in = x @ W_in + b_lstm : (2048x512)@(512x2048), bf16 MFMA
  gemm_bf16_mfma<<<dim3(16, 16), 256, 0, stream>>>(x_bf, WinT, b_l, zin, 2048, 2048);

  // fused 64-step LSTM scan (persistent, fence-free fine-grained coherence)
  lstm_coop<<<32, 512, 0, stream>>>(zin, WT, hm, rnn, bar);

  // predictions = rnn_out @ W_out + b_out : (2048x512)@(512x32000), bf16 MFMA
  gemm_bf16_mfma<<<dim3(250, 16), 256, 0, stream>>>(rnn, WoutT, b_o, out, 2048, 32000);
}

// Round 4
// 1533.896 us; speedup vs baseline: 1.0153x; 1.0153x over previous
//
#include <hip/hip_runtime.h>
#include <hip/hip_bf16.h>
#include <cstdint>
#include <cstddef>

// ---------------- JAX threefry2x32 (partitionable scheme) — FROZEN (verified R1)
struct TF2 { uint32_t a, b; };

__host__ __device__ constexpr uint32_t rotl32(uint32_t v, int r) {
  return (v << r) | (v >> (32 - r));
}

__host__ __device__ constexpr TF2 threefry2x32(uint32_t k0, uint32_t k1,
                                               uint32_t x0, uint32_t x1) {
  uint32_t ks0 = k0, ks1 = k1, ks2 = k0 ^ k1 ^ 0x1BD11BDAu;
  const int rotA[4] = {13, 15, 26, 6};
  const int rotB[4] = {17, 29, 16, 24};
  x0 += ks0; x1 += ks1;
  for (int i = 0; i < 5; ++i) {
    const int* rot = (i % 2 == 0) ? rotA : rotB;
    for (int j = 0; j < 4; ++j) {
      x0 += x1; x1 = rotl32(x1, rot[j]); x1 ^= x0;
    }
    uint32_t ks[3] = {ks0, ks1, ks2};
    x0 += ks[(i + 1) % 3];
    x1 += ks[(i + 2) % 3] + (uint32_t)(i + 1);
  }
  return TF2{x0, x1};
}

__device__ __forceinline__ float jax_mask(uint32_t child, uint32_t idx) {
  TF2 ck = threefry2x32(0u, 42u, 0u, child);   // constant-folds
  TF2 r  = threefry2x32(ck.a, ck.b, 0u, idx);
  uint32_t bits = r.a ^ r.b;
  float u = __uint_as_float((bits >> 9) | 0x3f800000u) - 1.0f;
  return (u < 0.7f) ? (1.0f / 0.7f) : 0.0f;
}

__device__ __forceinline__ unsigned short f2bf(float f) {
  uint32_t u = __float_as_uint(f);
  uint32_t r = (u + 0x7fffu + ((u >> 16) & 1u)) >> 16;   // RNE
  return (unsigned short)r;
}

__device__ __forceinline__ float bf2f(unsigned short b) {
  return __uint_as_float((uint32_t)b << 16);
}

typedef __attribute__((ext_vector_type(8))) short short8;
typedef __attribute__((ext_vector_type(4))) float f32x4;

// async global->LDS, 16B per lane. LDS dest = wave-uniform base + lane*16.
__device__ __forceinline__ void async_copy16(const unsigned short* g, unsigned short* l) {
  __builtin_amdgcn_global_load_lds(
      (const __attribute__((address_space(1))) unsigned int*)g,
      (__attribute__((address_space(3))) unsigned int*)l, 16, 0, 0);
}

// ---------------- build x (bf16) = [image_emb ; emb_table[targets]*word_mask]
__global__ __launch_bounds__(256) void build_x_kernel(
    const float* __restrict__ img, const int* __restrict__ tgt,
    const float* __restrict__ emb, unsigned short* __restrict__ x) {
  const int idx = blockIdx.x * 256 + threadIdx.x;   // b*32768 + t*512 + e
  const int e = idx & 511;
  const int t = (idx >> 9) & 63;
  const int b = idx >> 15;
  float v;
  if (t == 0) {
    v = img[b * 512 + e];
  } else {
    const int w = tgt[b * 64 + (t - 1)];
    const float wm = jax_mask(0u, (uint32_t)(b * 512 + e));
    v = emb[(size_t)w * 512 + e] * wm;
  }
  x[idx] = f2bf(v);
}

// ---------------- transpose W_rec (512x2048) -> WT (2048x512) fp32 -------
__global__ __launch_bounds__(256) void transpose_wrec(
    const float* __restrict__ in, float* __restrict__ out) {
  __shared__ float tile[32][33];
  const int j0 = blockIdx.x * 32;
  const int u0 = blockIdx.y * 32;
  const int tx = threadIdx.x & 31;
  const int ty = threadIdx.x >> 5;
  for (int r = ty; r < 32; r += 8)
    tile[r][tx] = in[(size_t)(u0 + r) * 2048 + (j0 + tx)];
  __syncthreads();
  for (int r = ty; r < 32; r += 8)
    out[(size_t)(j0 + r) * 512 + (u0 + tx)] = tile[tx][r];
}

// ------- transpose+convert fp32 [R][C] -> bf16 [C][R]  (R=512 here) ------
__global__ __launch_bounds__(256) void transpose_cvt(
    const float* __restrict__ in, unsigned short* __restrict__ out,
    int R, int C) {
  __shared__ float tile[32][33];
  const int c0 = blockIdx.x * 32;
  const int r0 = blockIdx.y * 32;
  const int tx = threadIdx.x & 31;
  const int ty = threadIdx.x >> 5;
  for (int r = ty; r < 32; r += 8)
    tile[r][tx] = in[(size_t)(r0 + r) * C + (c0 + tx)];
  __syncthreads();
  for (int r = ty; r < 32; r += 8)
    out[(size_t)(c0 + r) * R + (r0 + tx)] = f2bf(tile[tx][r]);
}

// ---------------- bf16 MFMA GEMM: C[M][N] = A[M][512] * BT[N][512]^T + bias
// 128x128 tile, BK=32, 16x16x32 MFMA, fp32 accum. m97 structure.
__global__ __launch_bounds__(256) void gemm_bf16_mfma(
    const unsigned short* __restrict__ A, const unsigned short* __restrict__ BT,
    const float* __restrict__ bias, float* __restrict__ C, int M, int N) {
  __shared__ unsigned short As[128 * 32];   // [m][k] rows of 32 bf16 (64B)
  __shared__ unsigned short Bs[128 * 32];   // [n][k]
  const int tid = threadIdx.x;
  const int lane = tid & 63;
  const int wave = tid >> 6;              // 0..3
  const int wm = (wave >> 1) * 64;
  const int wn = (wave & 1) * 64;
  const int m0 = blockIdx.y * 128;
  const int n0 = blockIdx.x * 128;

  f32x4 zero4 = {0.f, 0.f, 0.f, 0.f};
  f32x4 acc[4][4];
#pragma unroll
  for (int i = 0; i < 4; ++i)
#pragma unroll
    for (int j = 0; j < 4; ++j) acc[i][j] = zero4;

  // staging: thread covers row tid/4 (and +64), 16B chunk tid%4
  const unsigned short* ga = A + (size_t)(m0 + (tid >> 2)) * 512 + (tid & 3) * 8;
  const unsigned short* gb = BT + (size_t)(n0 + (tid >> 2)) * 512 + (tid & 3) * 8;
  unsigned short* lwA = As + wave * 512;   // + lane*16B by HW
  unsigned short* lwB = Bs + wave * 512;

  const int fr = lane & 15;
  const int kc = (lane >> 4) * 8;

  for (int k0 = 0; k0 < 512; k0 += 32) {
    __syncthreads();   // previous frag reads done before overwrite
    async_copy16(ga + k0, lwA);
    async_copy16(ga + k0 + 64 * 512, lwA + 2048);
    async_copy16(gb + k0, lwB);
    async_copy16(gb + k0 + 64 * 512, lwB + 2048);
    __syncthreads();   // drain vmcnt: LDS tiles ready

    short8 af[4], bf[4];
#pragma unroll
    for (int i = 0; i < 4; ++i)
      af[i] = *(const short8*)(As + (wm + i * 16 + fr) * 32 + kc);
#pragma unroll
    for (int i = 0; i < 4; ++i)
      bf[i] = *(const short8*)(Bs + (wn + i * 16 + fr) * 32 + kc);
#pragma unroll
    for (int mi = 0; mi < 4; ++mi)
#pragma unroll
      for (int ni = 0; ni < 4; ++ni)
        acc[mi][ni] = __builtin_amdgcn_mfma_f32_16x16x32_bf16(
            af[mi], bf[ni], acc[mi][ni], 0, 0, 0);
  }

  // epilogue: C row = quad*4+reg, col = lane&15 (m89-verified layout)
#pragma unroll
  for (int mi = 0; mi < 4; ++mi) {
    const int mrow = m0 + wm + mi * 16 + (lane >> 4) * 4;
#pragma unroll
    for (int ni = 0; ni < 4; ++ni) {
      const int ncol = n0 + wn + ni * 16 + (lane & 15);
      const float bs = bias[ncol];
#pragma unroll
      for (int r2 = 0; r2 < 4; ++r2)
        C[(size_t)(mrow + r2) * N + ncol] = acc[mi][ni][r2] + bs;
    }
  }
}

// ---------------- fused LSTM scan: ONE persistent kernel, 64 steps -------
// 32 blocks x 512 threads (8 waves; 1 block/CU). Waves 0-3: gates, K-half 0;
// waves 4-7: gates, K-half 1. W_rec frags (bf16 hi+lo) live in registers.
// h crosses blocks via PACKED uint32 planes accessed ONLY with relaxed
// AGENT-scope atomics (sc1 -> coherence point; no L1/L2 staleness).
// Grid sync = DECENTRALIZED flag barrier: each block stores flags[bid]=t+1
// to its own cacheline (no RMW contention), every block's wave 0 polls all
// 32 flags with one vector load until __all(f >= t+1). One L3 RTT instead
// of serialized atomicAdd chain + central release.
// hm word layout per parity: [plane hi=0/lo=1][gate][b][k/2], word =
// bf16(k) | bf16(k+1)<<16.  Words/parity = 2*4*32*256 = 65536 (256 KB).
#define HMW 65536
#define NBLK 32

__device__ __forceinline__ void grid_barrier(uint32_t* flags, int bid,
                                             uint32_t tgt, int wv, int lane) {
  asm volatile("s_waitcnt vmcnt(0)" ::: "memory");   // this wave's hm stores acked
  __syncthreads();                                    // => ALL waves' stores acked
  if (wv == 0) {
    if (lane == 0)
      __hip_atomic_store(flags + bid * 32, tgt,
                         __ATOMIC_RELAXED, __HIP_MEMORY_SCOPE_AGENT);
    const int sl = lane & 31;                         // lanes 32-63 mirror 0-31
    while (true) {
      const uint32_t f = __hip_atomic_load(flags + sl * 32,
                          __ATOMIC_RELAXED, __HIP_MEMORY_SCOPE_AGENT);
      if (__all((int)(f >= tgt))) break;
      __builtin_amdgcn_s_sleep(1);
    }
  }
  __syncthreads();
}

__device__ __forceinline__ unsigned long long hm_ld(const unsigned long long* p) {
  return __hip_atomic_load(p, __ATOMIC_RELAXED, __HIP_MEMORY_SCOPE_AGENT);
}

__global__ __launch_bounds__(512, 1) void lstm_coop(
    const float* __restrict__ zin, const float* __restrict__ WT,
    uint32_t* __restrict__ hm, unsigned short* __restrict__ rnn,
    uint32_t* __restrict__ flags) {
  __shared__ float zsh[2][4][32][17];
  const int tid = threadIdx.x;
  const int lane = tid & 63;
  const int wv = tid >> 6;                // 0..7
  const int g = wv & 3;                   // gate
  const int half = wv >> 2;               // K half (0: k<256, 1: k>=256)
  const int u0 = blockIdx.x * 16;
  const int fr = lane & 15;
  const int kq = (lane >> 4) * 8;

  // ---- one-time: W fragments (bf16 hi/lo) into registers ----------------
  // B-frag for 16x16x32: lane holds W[col = u0+fr][k = half*256 + j*32 + kq ..+8]
  short8 whi[8], wlo[8];
  {
    const float* wrow = WT + (size_t)(g * 512 + u0 + fr) * 512 + half * 256 + kq;
#pragma unroll
    for (int j = 0; j < 8; ++j) {
      const float4 w0 = *(const float4*)(wrow + j * 32);
      const float4 w1 = *(const float4*)(wrow + j * 32 + 4);
      const float wvv[8] = {w0.x, w0.y, w0.z, w0.w, w1.x, w1.y, w1.z, w1.w};
      short8 h8, l8;
#pragma unroll
      for (int e = 0; e < 8; ++e) {
        const unsigned short hb = f2bf(wvv[e]);
        h8[e] = (short)hb;
        l8[e] = (short)f2bf(wvv[e] - bf2f(hb));
      }
      whi[j] = h8; wlo[j] = l8;
    }
  }

  // ---- per-thread activation constants (512 threads = 512 cells) --------
  const int ab = tid >> 4;            // batch 0..31
  const int uc = tid & 15;
  const int au = u0 + uc;             // global u
  float rmask[4];
#pragma unroll
  for (int gg = 0; gg < 4; ++gg)
    rmask[gg] = jax_mask(1u, (uint32_t)((gg * 32 + ab) * 512 + au));
  float cs = 0.f;

  // per-lane hm qword bases (per parity; lo plane at +16384 qwords)
  const size_t qrow0 = ((size_t)((g * 32 + fr) * 256)) >> 1;      // row fr
  const size_t qk0   = qrow0 + (size_t)(half * 64) + (kq >> 2);   // + j*8

  for (int t = 0; t < 64; ++t) {
    const int rp = t & 1;             // read parity (t=0 skips reads)
    // prefetch zin (independent of barrier/hm)
    const size_t zo = (size_t)(ab * 64 + t) * 2048 + au;
    const float z0 = zin[zo], z1 = zin[zo + 512];
    const float z2 = zin[zo + 1024], z3 = zin[zo + 1536];

    f32x4 ahh0 = {0,0,0,0}, ahl0 = {0,0,0,0}, alh0 = {0,0,0,0};
    f32x4 ahh1 = {0,0,0,0}, ahl1 = {0,0,0,0}, alh1 = {0,0,0,0};

    if (t) {
      const unsigned long long* q =
          (const unsigned long long*)(hm + (size_t)rp * HMW);
#pragma unroll
      for (int j = 0; j < 8; ++j) {
        const size_t qo = qk0 + (size_t)(j * 8);
        union { unsigned long long w[2]; short8 s; } h0, h1, l0, l1;
        h0.w[0] = hm_ld(q + qo);             h0.w[1] = hm_ld(q + qo + 1);
        h1.w[0] = hm_ld(q + qo + 2048);      h1.w[1] = hm_ld(q + qo + 2049);
        l0.w[0] = hm_ld(q + qo + 16384);     l0.w[1] = hm_ld(q + qo + 16385);
        l1.w[0] = hm_ld(q + qo + 18432);     l1.w[1] = hm_ld(q + qo + 18433);
        ahh0 = __builtin_amdgcn_mfma_f32_16x16x32_bf16(h0.s, whi[j], ahh0, 0, 0, 0);
        ahh1 = __builtin_amdgcn_mfma_f32_16x16x32_bf16(h1.s, whi[j], ahh1, 0, 0, 0);
        ahl0 = __builtin_amdgcn_mfma_f32_16x16x32_bf16(h0.s, wlo[j], ahl0, 0, 0, 0);
        ahl1 = __builtin_amdgcn_mfma_f32_16x16x32_bf16(h1.s, wlo[j], ahl1, 0, 0, 0);
        alh0 = __builtin_amdgcn_mfma_f32_16x16x32_bf16(l0.s, whi[j], alh0, 0, 0, 0);
        alh1 = __builtin_amdgcn_mfma_f32_16x16x32_bf16(l1.s, whi[j], alh1, 0, 0, 0);
      }
    }

    // scatter partial z_rec to LDS: row = (lane>>4)*4 + r (+16), col = fr
#pragma unroll
    for (int r = 0; r < 4; ++r) {
      zsh[half][g][(lane >> 4) * 4 + r][fr]      = ahh0[r] + ahl0[r] + alh0[r];
      zsh[half][g][16 + (lane >> 4) * 4 + r][fr] = ahh1[r] + ahl1[r] + alh1[r];
    }
    __syncthreads();

    // activation: 1 cell per thread (b = ab, u = au)
    const float zi = zsh[0][0][ab][uc] + zsh[1][0][ab][uc] + z0;
    const float zf = zsh[0][1][ab][uc] + zsh[1][1][ab][uc] + z1;
    const float zg = zsh[0][2][ab][uc] + zsh[1][2][ab][uc] + z2;
    const float zz = zsh[0][3][ab][uc] + zsh[1][3][ab][uc] + z3;
    const float i_ = 1.f / (1.f + expf(-zi));
    const float f_ = 1.f / (1.f + expf(-zf));
    const float g_ = tanhf(zg);
    const float o_ = 1.f / (1.f + expf(-zz));
    cs = f_ * cs + i_ * g_;
    const float hn = o_ * tanhf(cs);
    const float fm = jax_mask(2u, (uint32_t)((ab * 64 + t) * 512 + au));
    rnn[(size_t)(ab * 64 + t) * 512 + au] = f2bf(hn * fm);

    if (t < 63) {
      // write masked h (packed hi|lo planes) for next step, opposite parity
      uint32_t* hw = hm + (size_t)(rp ^ 1) * HMW;
      const int kp = au >> 1;
#pragma unroll
      for (int gg = 0; gg < 4; ++gg) {
        const float v = hn * rmask[gg];
        const unsigned short hb16 = f2bf(v);
        const unsigned short lb16 = f2bf(v - bf2f(hb16));
        const unsigned mine = (unsigned)hb16 | ((unsigned)lb16 << 16);
        const unsigned oth = (unsigned)__shfl_xor((int)mine, 1, 64);
        if (!(uc & 1)) {
          const unsigned hiw = (mine & 0xFFFFu) | (oth << 16);
          const unsigned low = (mine >> 16) | (oth & 0xFFFF0000u);
          const size_t wi = (size_t)(gg * 32 + ab) * 256 + kp;
          __hip_atomic_store(hw + wi, hiw,
                             __ATOMIC_RELAXED, __HIP_MEMORY_SCOPE_AGENT);
          __hip_atomic_store(hw + 32768 + wi, low,
                             __ATOMIC_RELAXED, __HIP_MEMORY_SCOPE_AGENT);
        }
      }
      // grid-wide flag barrier: all hm writes visible before anyone reads
      grid_barrier(flags, blockIdx.x, (uint32_t)(t + 1), wv, lane);
    }
  }
}

// ---------------- launch -------------------------------------------------
extern "C" void kernel_launch(void* const* d_in, const int* in_sizes, int n_in,
                              void* d_out, int out_size, void* d_ws, size_t ws_size,
                              hipStream_t stream) {
  (void)in_sizes; (void)n_in; (void)out_size; (void)ws_size;
  const float* img   = (const float*)d_in[1];
  const int*   tgt   = (const int*)d_in[2];
  const float* emb   = (const float*)d_in[3];
  const float* W_in  = (const float*)d_in[4];
  const float* W_rec = (const float*)d_in[5];
  const float* b_l   = (const float*)d_in[6];
  const float* W_out = (const float*)d_in[7];
  const float* b_o   = (const float*)d_in[8];
  float* out = (float*)d_out;
  float* ws  = (float*)d_ws;

  float* zin = ws;                       // 4,194,304 f (16 MB)
  float* WT  = ws + 4194304;             // 1,048,576 f (4 MB)
  uint32_t* hm = (uint32_t*)(ws + 5242880);  // 2*HMW words (512 KB)
  uint32_t* flags = (uint32_t*)(ws + 5440000);  // 32 x 128B flag slots (4 KB)
  unsigned short* us = (unsigned short*)(ws + 5455872);
  unsigned short* x_bf  = us;            // 1,048,576 us (2 MB)
  unsigned short* WinT  = us + 1048576;  // 1,048,576 us
  unsigned short* rnn   = us + 2097152;  // 1,048,576 us
  unsigned short* WoutT = us + 3145728;  // 16,384,000 us (32.8 MB)

  hipMemsetAsync(flags, 0, 4096, stream);    // reset barrier flags

  build_x_kernel<<<4096, 256, 0, stream>>>(img, tgt, emb, x_bf);
  transpose_wrec<<<dim3(64, 16), 256, 0, stream>>>(W_rec, WT);
  transpose_cvt<<<dim3(64, 16), 256, 0, stream>>>(W_in, WinT, 512, 2048);
  transpose_cvt<<<dim3(1000, 16), 256, 0, stream>>>(W_out, WoutT, 512, 32000);

  // z_in = x @ W_in + b_lstm : (2048x512)@(512x2048), bf16 MFMA
  gemm_bf16_mfma<<<dim3(16, 16), 256, 0, stream>>>(x_bf, WinT, b_l, zin, 2048, 2048);

  // fused 64-step LSTM scan (persistent, flag-barrier grid sync)
  lstm_coop<<<32, 512, 0, stream>>>(zin, WT, hm, rnn, flags);

  // predictions = rnn_out @ W_out + b_out : (2048x512)@(512x32000), bf16 MFMA
  gemm_bf16_mfma<<<dim3(250, 16), 256, 0, stream>>>(rnn, WoutT, b_o, out, 2048, 32000);
}

// Round 6
// 1149.161 us; speedup vs baseline: 1.3552x; 1.3348x over previous
//
#include <hip/hip_runtime.h>
#include <hip/hip_bf16.h>
#include <cstdint>
#include <cstddef>

// ---------------- JAX threefry2x32 (partitionable scheme) — FROZEN (verified R1)
struct TF2 { uint32_t a, b; };

__host__ __device__ constexpr uint32_t rotl32(uint32_t v, int r) {
  return (v << r) | (v >> (32 - r));
}

__host__ __device__ constexpr TF2 threefry2x32(uint32_t k0, uint32_t k1,
                                               uint32_t x0, uint32_t x1) {
  uint32_t ks0 = k0, ks1 = k1, ks2 = k0 ^ k1 ^ 0x1BD11BDAu;
  const int rotA[4] = {13, 15, 26, 6};
  const int rotB[4] = {17, 29, 16, 24};
  x0 += ks0; x1 += ks1;
  for (int i = 0; i < 5; ++i) {
    const int* rot = (i % 2 == 0) ? rotA : rotB;
    for (int j = 0; j < 4; ++j) {
      x0 += x1; x1 = rotl32(x1, rot[j]); x1 ^= x0;
    }
    uint32_t ks[3] = {ks0, ks1, ks2};
    x0 += ks[(i + 1) % 3];
    x1 += ks[(i + 2) % 3] + (uint32_t)(i + 1);
  }
  return TF2{x0, x1};
}

__device__ __forceinline__ float jax_mask(uint32_t child, uint32_t idx) {
  TF2 ck = threefry2x32(0u, 42u, 0u, child);   // constant-folds
  TF2 r  = threefry2x32(ck.a, ck.b, 0u, idx);
  uint32_t bits = r.a ^ r.b;
  float u = __uint_as_float((bits >> 9) | 0x3f800000u) - 1.0f;
  return (u < 0.7f) ? (1.0f / 0.7f) : 0.0f;
}

__device__ __forceinline__ unsigned short f2bf(float f) {
  uint32_t u = __float_as_uint(f);
  uint32_t r = (u + 0x7fffu + ((u >> 16) & 1u)) >> 16;   // RNE
  return (unsigned short)r;
}

__device__ __forceinline__ float bf2f(unsigned short b) {
  return __uint_as_float((uint32_t)b << 16);
}

typedef __attribute__((ext_vector_type(8))) short short8;
typedef __attribute__((ext_vector_type(4))) float f32x4;

// async global->LDS, 16B per lane. LDS dest = wave-uniform base + lane*16.
__device__ __forceinline__ void async_copy16(const unsigned short* g, unsigned short* l) {
  __builtin_amdgcn_global_load_lds(
      (const __attribute__((address_space(1))) unsigned int*)g,
      (__attribute__((address_space(3))) unsigned int*)l, 16, 0, 0);
}

// ---------------- build x (bf16) = [image_emb ; emb_table[targets]*word_mask]
__global__ __launch_bounds__(256) void build_x_kernel(
    const float* __restrict__ img, const int* __restrict__ tgt,
    const float* __restrict__ emb, unsigned short* __restrict__ x) {
  const int idx = blockIdx.x * 256 + threadIdx.x;   // b*32768 + t*512 + e
  const int e = idx & 511;
  const int t = (idx >> 9) & 63;
  const int b = idx >> 15;
  float v;
  if (t == 0) {
    v = img[b * 512 + e];
  } else {
    const int w = tgt[b * 64 + (t - 1)];
    const float wm = jax_mask(0u, (uint32_t)(b * 512 + e));
    v = emb[(size_t)w * 512 + e] * wm;
  }
  x[idx] = f2bf(v);
}

// ---------------- recurrent dropout masks (4,B,U), pre-scaled -----------
__global__ __launch_bounds__(256) void rec_mask_kernel(float* __restrict__ rm) {
  const int idx = blockIdx.x * 256 + threadIdx.x;
  rm[idx] = jax_mask(1u, (uint32_t)idx);
}

// --- transpose W_rec (512x2048) -> bf16 hi/lo planes (2048x512) ---------
// out row j = gate*512 + out_unit, col = k (input unit). Fragment-ready.
__global__ __launch_bounds__(256) void transpose_wrec_hilo(
    const float* __restrict__ in, unsigned short* __restrict__ hi,
    unsigned short* __restrict__ lo) {
  __shared__ float tile[32][33];
  const int j0 = blockIdx.x * 32;
  const int u0 = blockIdx.y * 32;
  const int tx = threadIdx.x & 31;
  const int ty = threadIdx.x >> 5;
  for (int r = ty; r < 32; r += 8)
    tile[r][tx] = in[(size_t)(u0 + r) * 2048 + (j0 + tx)];
  __syncthreads();
  for (int r = ty; r < 32; r += 8) {
    const float v = tile[tx][r];
    const unsigned short hb = f2bf(v);
    hi[(size_t)(j0 + r) * 512 + (u0 + tx)] = hb;
    lo[(size_t)(j0 + r) * 512 + (u0 + tx)] = f2bf(v - bf2f(hb));
  }
}

// ------- transpose+convert fp32 [R][C] -> bf16 [C][R]  (R=512 here) ------
__global__ __launch_bounds__(256) void transpose_cvt(
    const float* __restrict__ in, unsigned short* __restrict__ out,
    int R, int C) {
  __shared__ float tile[32][33];
  const int c0 = blockIdx.x * 32;
  const int r0 = blockIdx.y * 32;
  const int tx = threadIdx.x & 31;
  const int ty = threadIdx.x >> 5;
  for (int r = ty; r < 32; r += 8)
    tile[r][tx] = in[(size_t)(r0 + r) * C + (c0 + tx)];
  __syncthreads();
  for (int r = ty; r < 32; r += 8)
    out[(size_t)(c0 + r) * R + (r0 + tx)] = f2bf(tile[tx][r]);
}

// ---------------- bf16 MFMA GEMM: C[M][N] = A[M][512] * BT[N][512]^T + bias
// 128x128 tile, BK=32, 16x16x32 MFMA, fp32 accum. m97 structure.
__global__ __launch_bounds__(256) void gemm_bf16_mfma(
    const unsigned short* __restrict__ A, const unsigned short* __restrict__ BT,
    const float* __restrict__ bias, float* __restrict__ C, int M, int N) {
  __shared__ unsigned short As[128 * 32];   // [m][k] rows of 32 bf16 (64B)
  __shared__ unsigned short Bs[128 * 32];   // [n][k]
  const int tid = threadIdx.x;
  const int lane = tid & 63;
  const int wave = tid >> 6;              // 0..3
  const int wm = (wave >> 1) * 64;
  const int wn = (wave & 1) * 64;
  const int m0 = blockIdx.y * 128;
  const int n0 = blockIdx.x * 128;

  f32x4 zero4 = {0.f, 0.f, 0.f, 0.f};
  f32x4 acc[4][4];
#pragma unroll
  for (int i = 0; i < 4; ++i)
#pragma unroll
    for (int j = 0; j < 4; ++j) acc[i][j] = zero4;

  // staging: thread covers row tid/4 (and +64), 16B chunk tid%4
  const unsigned short* ga = A + (size_t)(m0 + (tid >> 2)) * 512 + (tid & 3) * 8;
  const unsigned short* gb = BT + (size_t)(n0 + (tid >> 2)) * 512 + (tid & 3) * 8;
  unsigned short* lwA = As + wave * 512;   // + lane*16B by HW
  unsigned short* lwB = Bs + wave * 512;

  const int fr = lane & 15;
  const int kc = (lane >> 4) * 8;

  for (int k0 = 0; k0 < 512; k0 += 32) {
    __syncthreads();   // previous frag reads done before overwrite
    async_copy16(ga + k0, lwA);
    async_copy16(ga + k0 + 64 * 512, lwA + 2048);
    async_copy16(gb + k0, lwB);
    async_copy16(gb + k0 + 64 * 512, lwB + 2048);
    __syncthreads();   // drain vmcnt: LDS tiles ready

    short8 af[4], bf[4];
#pragma unroll
    for (int i = 0; i < 4; ++i)
      af[i] = *(const short8*)(As + (wm + i * 16 + fr) * 32 + kc);
#pragma unroll
    for (int i = 0; i < 4; ++i)
      bf[i] = *(const short8*)(Bs + (wn + i * 16 + fr) * 32 + kc);
#pragma unroll
    for (int mi = 0; mi < 4; ++mi)
#pragma unroll
      for (int ni = 0; ni < 4; ++ni)
        acc[mi][ni] = __builtin_amdgcn_mfma_f32_16x16x32_bf16(
            af[mi], bf[ni], acc[mi][ni], 0, 0, 0);
  }

  // epilogue: C row = quad*4+reg, col = lane&15 (m89-verified layout)
#pragma unroll
  for (int mi = 0; mi < 4; ++mi) {
    const int mrow = m0 + wm + mi * 16 + (lane >> 4) * 4;
#pragma unroll
    for (int ni = 0; ni < 4; ++ni) {
      const int ncol = n0 + wn + ni * 16 + (lane & 15);
      const float bs = bias[ncol];
#pragma unroll
      for (int r2 = 0; r2 < 4; ++r2)
        C[(size_t)(mrow + r2) * N + ncol] = acc[mi][ni][r2] + bs;
    }
  }
}

// ---------------- one LSTM time step (v4: MFMA, no LDS staging) ----------
// grid dim3(32,2): x = u-tile (16 cols), y = b-group (16 rows). 512 thr =
// 8 waves = (4 gates x 2 K-halves). A = masked-h bf16 hi/lo planes in
// global (L2-hot, 256 KB/parity); W = precomputed bf16 hi/lo (L2-hot).
// 3-product MFMA (Ah*Wh + Ah*Wl + Al*Wh) ~= fp32 recurrence.
// am layout [parity][gate][plane][b 32][k 512] us; strides: plane 16384,
// gate 32768, parity 131072. Launch boundary = grid sync (coherent).
__global__ __launch_bounds__(512) void lstm_step3(
    const float* __restrict__ zin, const unsigned short* __restrict__ whi,
    const unsigned short* __restrict__ wlo, const float* __restrict__ rm,
    unsigned short* __restrict__ am, float* __restrict__ c,
    unsigned short* __restrict__ rnn, const int t) {
  __shared__ float zsh[2][4][16][17];
  const int tid = threadIdx.x;
  const int lane = tid & 63;
  const int wv = tid >> 6;            // 0..7
  const int g = wv & 3;               // gate
  const int kh = wv >> 2;             // K half
  const int u0 = blockIdx.x * 16;
  const int b0 = blockIdx.y * 16;
  const int fr = lane & 15;
  const int kq = (lane >> 4) * 8;
  const int rp = t & 1;

  f32x4 ahh = {0,0,0,0}, ahl = {0,0,0,0}, alh = {0,0,0,0};

  // A-frag: lane holds am[rp][g][p][b0+fr][kh*256 + j*32 + kq ..+8]
  const unsigned short* abase = am + (size_t)rp * 131072
      + (size_t)g * 32768 + (size_t)(b0 + fr) * 512 + kh * 256 + kq;
  // W-frag: lane holds w[(g*512 + u0+fr)][kh*256 + j*32 + kq ..+8]
  const size_t woff = (size_t)(g * 512 + u0 + fr) * 512 + kh * 256 + kq;
  const unsigned short* wh = whi + woff;
  const unsigned short* wl = wlo + woff;

#pragma unroll
  for (int j = 0; j < 8; ++j) {
    const short8 ah = *(const short8*)(abase + j * 32);
    const short8 al = *(const short8*)(abase + 16384 + j * 32);
    const short8 w0 = *(const short8*)(wh + j * 32);
    const short8 w1 = *(const short8*)(wl + j * 32);
    ahh = __builtin_amdgcn_mfma_f32_16x16x32_bf16(ah, w0, ahh, 0, 0, 0);
    ahl = __builtin_amdgcn_mfma_f32_16x16x32_bf16(ah, w1, ahl, 0, 0, 0);
    alh = __builtin_amdgcn_mfma_f32_16x16x32_bf16(al, w0, alh, 0, 0, 0);
  }

  // scatter z_rec partial: row b = (lane>>4)*4 + r, col u = fr
#pragma unroll
  for (int r = 0; r < 4; ++r)
    zsh[kh][g][(lane >> 4) * 4 + r][fr] = ahh[r] + ahl[r] + alh[r];
  __syncthreads();

  if (tid < 256) {
    const int bl = tid >> 4, ul = tid & 15;
    const int b = b0 + bl, u = u0 + ul;
    const size_t zo = (size_t)(b * 64 + t) * 2048 + u;
    const float zi = zsh[0][0][bl][ul] + zsh[1][0][bl][ul] + zin[zo];
    const float zf = zsh[0][1][bl][ul] + zsh[1][1][bl][ul] + zin[zo + 512];
    const float zg = zsh[0][2][bl][ul] + zsh[1][2][bl][ul] + zin[zo + 1024];
    const float zz = zsh[0][3][bl][ul] + zsh[1][3][bl][ul] + zin[zo + 1536];
    const float i_ = 1.f / (1.f + expf(-zi));
    const float f_ = 1.f / (1.f + expf(-zf));
    const float g_ = tanhf(zg);
    const float o_ = 1.f / (1.f + expf(-zz));
    const size_t cidx = (size_t)b * 512 + u;
    const float cn = f_ * c[cidx] + i_ * g_;
    c[cidx] = cn;
    const float hn = o_ * tanhf(cn);
    const float fm = jax_mask(2u, (uint32_t)((b * 64 + t) * 512 + u));
    rnn[(size_t)(b * 64 + t) * 512 + u] = f2bf(hn * fm);

    // write masked h (hi + lo residual) for next step, opposite parity
    unsigned short* aw = am + (size_t)(rp ^ 1) * 131072;
#pragma unroll
    for (int gg = 0; gg < 4; ++gg) {
      const float v = hn * rm[(size_t)(gg * 32 + b) * 512 + u];
      const unsigned short hb = f2bf(v);
      aw[(size_t)gg * 32768 + (size_t)b * 512 + u] = hb;
      aw[(size_t)gg * 32768 + 16384 + (size_t)b * 512 + u] = f2bf(v - bf2f(hb));
    }
  }
}

// ---------------- launch -------------------------------------------------
extern "C" void kernel_launch(void* const* d_in, const int* in_sizes, int n_in,
                              void* d_out, int out_size, void* d_ws, size_t ws_size,
                              hipStream_t stream) {
  (void)in_sizes; (void)n_in; (void)out_size; (void)ws_size;
  const float* img   = (const float*)d_in[1];
  const int*   tgt   = (const int*)d_in[2];
  const float* emb   = (const float*)d_in[3];
  const float* W_in  = (const float*)d_in[4];
  const float* W_rec = (const float*)d_in[5];
  const float* b_l   = (const float*)d_in[6];
  const float* W_out = (const float*)d_in[7];
  const float* b_o   = (const float*)d_in[8];
  float* out = (float*)d_out;
  float* ws  = (float*)d_ws;

  float* zin = ws;                         // 4,194,304 f (16 MB)
  float* rm  = ws + 4194304;               //    65,536 f (256 KB)
  float* c   = ws + 4259840;               //    16,384 f (64 KB)
  unsigned short* us = (unsigned short*)(ws + 4276224);
  unsigned short* am    = us;              //   262,144 us (512 KB, 2 parities)
  unsigned short* whi   = us + 262144;     // 1,048,576 us (2 MB)
  unsigned short* wlo   = us + 1310720;    // 1,048,576 us
  unsigned short* x_bf  = us + 2359296;    // 1,048,576 us
  unsigned short* WinT  = us + 3407872;    // 1,048,576 us
  unsigned short* rnn   = us + 4456448;    // 1,048,576 us
  unsigned short* WoutT = us + 5505024;    // 16,384,000 us (~58 MB total ws)

  hipMemsetAsync(am, 0, 262144 * sizeof(unsigned short), stream);  // h0 = 0
  hipMemsetAsync(c, 0, 16384 * sizeof(float), stream);             // c0 = 0

  build_x_kernel<<<4096, 256, 0, stream>>>(img, tgt, emb, x_bf);
  rec_mask_kernel<<<256, 256, 0, stream>>>(rm);
  transpose_wrec_hilo<<<dim3(64, 16), 256, 0, stream>>>(W_rec, whi, wlo);
  transpose_cvt<<<dim3(64, 16), 256, 0, stream>>>(W_in, WinT, 512, 2048);
  transpose_cvt<<<dim3(1000, 16), 256, 0, stream>>>(W_out, WoutT, 512, 32000);

  // z_in = x @ W_in + b_lstm : (2048x512)@(512x2048), bf16 MFMA
  gemm_bf16_mfma<<<dim3(16, 16), 256, 0, stream>>>(x_bf, WinT, b_l, zin, 2048, 2048);

  // 64-step LSTM scan: MFMA step kernel, launch boundary = grid sync
  for (int t = 0; t < 64; ++t)
    lstm_step3<<<dim3(32, 2), 512, 0, stream>>>(zin, whi, wlo, rm, am, c, rnn, t);

  // predictions = rnn_out @ W_out + b_out : (2048x512)@(512x32000), bf16 MFMA
  gemm_bf16_mfma<<<dim3(250, 16), 256, 0, stream>>>(rnn, WoutT, b_o, out, 2048, 32000);
}